// Round 2
// baseline (350.856 us; speedup 1.0000x reference)
//
#include <hip/hip_runtime.h>

typedef unsigned int u32;
typedef unsigned char u8;
typedef int i32x4 __attribute__((ext_vector_type(4)));
typedef int i32x16 __attribute__((ext_vector_type(16)));

// Workspace layout:
//   [0, 589824)          Wm[tap=r*3+s][oc][ic]  i8  (+/-1 weights)
//   [589824, +27570176)  Xp[n][h'][w'][ic] i8, h',w' in [0,58) (zero halo),
//                        ic-byte pre-swizzled by ((w'&7)<<4); row stride 14848.
#define WM_OFF 0
#define XP_OFF 589824
#define XROW 14848   // 58*256

// ---------------------------------------------------------------------------
// Kernel 1: decode codebook -> i8 +/-1 weights, layout [tap][oc][ic].
// idx = pos*65536 + o*256 + i  (coalesced writes; enc/cb gathers are L2-hot).
// ---------------------------------------------------------------------------
__global__ __launch_bounds__(256) void pack_w_i8(const int* __restrict__ enc,
                                                 const float* __restrict__ cb,
                                                 char* __restrict__ wm) {
    int idx = blockIdx.x * 256 + threadIdx.x;       // 0..589823 = 9*256*256
    int i   = idx & 255;
    int o   = (idx >> 8) & 255;
    int pos = idx >> 16;                            // 0..8
    int f = o * 2304 + i * 9 + pos;                 // OIHW flat index
    int j = f / 12;
    int t = f - j * 12;
    float v = cb[enc[j] * 12 + t];
    wm[idx] = v < 0.f ? (char)-1 : (char)1;
}

// ---------------------------------------------------------------------------
// Kernel 2: binarize x to NHWC i8 with zero halo + w-keyed swizzle.
// Block (hh, n), hh in [0,58). Read coalesced (lane=w, loop c), transpose via
// LDS (b32 writes), write 14.8 KB/row fully coalesced uint4. Halo rows/cols
// written as zeros -> whole Xp region rewritten every launch (no memset).
// ---------------------------------------------------------------------------
__global__ __launch_bounds__(256) void pack_x_i8(const float* __restrict__ x,
                                                 u8* __restrict__ xp) {
    __shared__ __align__(16) u8 xl[14336];          // [w 0..55][256 ic] swizzled
    int hh = blockIdx.x;
    int n  = blockIdx.y;
    int t  = threadIdx.x;
    u8* dst = xp + (size_t)(n * 58 + hh) * XROW;
    uint4 z = make_uint4(0u, 0u, 0u, 0u);
    if (hh == 0 || hh == 57) {                      // zero halo rows
        for (int g = t; g < 928; g += 256) *(uint4*)(dst + g * 16) = z;
        return;
    }
    int h = hh - 1;
    int cw = t >> 6, lane = t & 63;
    if (lane < 56) {
        int w = lane;
        const float* xq = x + (size_t)(n * 256 + cw * 64) * 3136 + h * 56 + w;
        int sw = ((w + 1) & 7) << 4;                // swizzle key = w' = w+1
#pragma unroll 4
        for (int cq = 0; cq < 16; ++cq) {
            u32 qv = 0;
#pragma unroll
            for (int j2 = 0; j2 < 4; ++j2) {
                float v = xq[(size_t)(cq * 4 + j2) * 3136];
                qv |= (v < 0.f ? 0xFFu : 0x01u) << (8 * j2);
            }
            *(u32*)&xl[w * 256 + ((cw * 64 + cq * 4) ^ sw)] = qv;
        }
    }
    __syncthreads();
    // row out: [w'=0 zeros][w'=1..56 from LDS][w'=57 zeros]
    for (int g = t; g < 928; g += 256) {
        uint4 v = z;
        if (g >= 16 && g < 912) v = *(const uint4*)&xl[(g - 16) * 16];
        *(uint4*)(dst + g * 16) = v;
    }
}

// ---------------------------------------------------------------------------
// Kernel 3: i8 MFMA conv. Block = 512 thr (8 waves) = 256 oc x 128 px
// (2 output rows of one image). Wave (ocg=wave&3, pxg=wave>>2) owns
// 64 oc x 64 px = 2x2 tiles of 32x32. X tile (4 padded rows, 59392 B
// CONTIGUOUS in Xp) staged to LDS once -> barrier-free K-loop:
// 72 steps x {2 A global (L2-hot weights), 2 swizzled ds_read_b128, 4 MFMA}.
// A-frag: lane row=oc=l&31, ic = kc*32 + (l>>5)*16 + e (16 B contiguous).
// B-frag: lane col=px=l&31, SAME ic indexing (consistency is what matters).
// C/D: col=l&31 (px), row=(q&3)+8*(q>>2)+4*(l>>5) (oc) [guide section 3,
// HW-verified, dtype-independent].
// ---------------------------------------------------------------------------
__global__ __launch_bounds__(512, 4) void conv_mfma(const u8* __restrict__ xp,
                                                    const char* __restrict__ wm,
                                                    float* __restrict__ y) {
    __shared__ __align__(16) u8 xl[61440];          // 4*14848 + slack for w'<=65 reads
    int t  = threadIdx.x;
    int n  = blockIdx.y;
    int h0 = blockIdx.x * 2;
    const u8* src = xp + (size_t)(n * 58 + h0) * XROW;   // rows h0..h0+3
    for (int g = t; g < 3712; g += 512)
        *(uint4*)&xl[g * 16] = *(const uint4*)(src + (size_t)g * 16);
    __syncthreads();

    int wave = t >> 6, lane = t & 63;
    int ocg = wave & 3;
    int pxg = wave >> 2;
    int col = lane & 31;
    int half = lane >> 5;
    int ocw = ocg * 64;

    i32x16 acc[2][2] = {};
    const char* wl = wm + (size_t)(ocw + col) * 256;   // R1 fix: half*16 was
    // added here AND inside kb -> half=1 lanes read ic+16 shifted A frags.
    // w' = bt*32 + col + s ; bt*32 == 0 (mod 8) -> swizzle depends on s only
    int sw0 = ((col + 0) & 7) << 4;
    int sw1 = ((col + 1) & 7) << 4;
    int sw2 = ((col + 2) & 7) << 4;
    int cb0 = (col + 0) * 256;
    int cb1 = (col + 1) * 256;
    int cb2 = (col + 2) * 256;

#pragma unroll 1
    for (int kc = 0; kc < 8; ++kc) {
        int kb = kc * 32 + half * 16;
        int kx0 = kb ^ sw0, kx1 = kb ^ sw1, kx2 = kb ^ sw2;
#pragma unroll
        for (int r = 0; r < 3; ++r) {
            int rowb = (pxg + r) * XROW;
#pragma unroll
            for (int s = 0; s < 3; ++s) {
                int tap = r * 3 + s;
                i32x4 a0 = *(const i32x4*)(wl + (size_t)tap * 65536 + kb);
                i32x4 a1 = *(const i32x4*)(wl + (size_t)tap * 65536 + 8192 + kb);
                int b0a = rowb + (s == 0 ? cb0 + kx0 : (s == 1 ? cb1 + kx1 : cb2 + kx2));
                i32x4 b0 = *(const i32x4*)&xl[b0a];
                i32x4 b1 = *(const i32x4*)&xl[b0a + 8192];   // w' + 32, same swizzle
                acc[0][0] = __builtin_amdgcn_mfma_i32_32x32x32_i8(a0, b0, acc[0][0], 0, 0, 0);
                acc[0][1] = __builtin_amdgcn_mfma_i32_32x32x32_i8(a0, b1, acc[0][1], 0, 0, 0);
                acc[1][0] = __builtin_amdgcn_mfma_i32_32x32x32_i8(a1, b0, acc[1][0], 0, 0, 0);
                acc[1][1] = __builtin_amdgcn_mfma_i32_32x32x32_i8(a1, b1, acc[1][1], 0, 0, 0);
            }
        }
    }

    int h = h0 + pxg;
    float* yb = y + (size_t)n * 256 * 3136 + (size_t)h * 56;
#pragma unroll
    for (int at = 0; at < 2; ++at) {
#pragma unroll
        for (int bt = 0; bt < 2; ++bt) {
            int w = bt * 32 + col;
            if (w < 56) {
#pragma unroll
                for (int q = 0; q < 16; ++q) {
                    int oc = ocw + at * 32 + (q & 3) + 8 * (q >> 2) + 4 * half;
                    yb[(size_t)oc * 3136 + w] = (float)acc[at][bt][q];
                }
            }
        }
    }
}

extern "C" void kernel_launch(void* const* d_in, const int* in_sizes, int n_in,
                              void* d_out, int out_size, void* d_ws, size_t ws_size,
                              hipStream_t stream) {
    const float* x  = (const float*)d_in[0];
    // d_in[1] (latent weight) unused in the STE forward value.
    const float* cb = (const float*)d_in[2];
    const int* enc  = (const int*)d_in[3];
    float* y        = (float*)d_out;

    char* wmc = (char*)d_ws + WM_OFF;
    u8*   xpp = (u8*)d_ws + XP_OFF;

    hipLaunchKernelGGL(pack_w_i8, dim3(2304), dim3(256), 0, stream, enc, cb, wmc);
    hipLaunchKernelGGL(pack_x_i8, dim3(58, 32), dim3(256), 0, stream, x, xpp);
    hipLaunchKernelGGL(conv_mfma, dim3(28, 32), dim3(512), 0, stream, xpp, wmc, y);
}